// Round 3
// baseline (477.975 us; speedup 1.0000x reference)
//
#include <hip/hip_runtime.h>

// ---------------------------------------------------------------------------
// CDiTBlock: complex DiT block on MI355X.
// Stages: convert weights->bf16 | ada (silu+clinear, fp32) | LN1+mod ->bf16
//         QKV cgemm (q pre-scaled 0.125*log2e, V written TRANSPOSED [bh][d][t])
//         flash complex attention (barrier-free: per-wave independent,
//             K/V^T fragments direct from L2, P via private LDS, DPP reduce,
//             exp2-domain softmax)
//         O-proj cgemm (+gate_a,+x residual, fp32) | LN2+mod ->bf16
//         f1 cgemm (+tanh-gelu) | f2 cgemm (+gate_m,+x2 residual -> d_out)
// All matmuls: bf16 MFMA 16x16x32, fp32 accum. GEMM tiles 64x64, BK=64, ld=72.
// ---------------------------------------------------------------------------

typedef unsigned short u16;
typedef __attribute__((ext_vector_type(8))) __bf16 bf16x8;
typedef __attribute__((ext_vector_type(8))) u16    u16x8;
typedef __attribute__((ext_vector_type(4))) u16    u16x4;
typedef __attribute__((ext_vector_type(4))) float  f32x4;

#define MFMA16(a, b, c) __builtin_amdgcn_mfma_f32_16x16x32_bf16(a, b, c, 0, 0, 0)

static constexpr int Bd = 4, Td = 1024, Dd = 512, Hd = 8, DHd = 64, MLPd = 2048;

__device__ __forceinline__ u16 f2bf(float x) {
  return __builtin_bit_cast(u16, (__bf16)x);
}
__device__ __forceinline__ float exp2fast(float x) {
  return __builtin_amdgcn_exp2f(x);   // v_exp_f32: D = 2^S0
}
__device__ __forceinline__ bf16x8 ldsfrag(const u16* p) {
  return __builtin_bit_cast(bf16x8, *(const u16x8*)p);
}
__device__ __forceinline__ bf16x8 gfrag(const u16* p) {
  return __builtin_bit_cast(bf16x8, *(const u16x8*)p);
}
__device__ __forceinline__ bf16x8 negbf(bf16x8 v) {
  u16x8 u = __builtin_bit_cast(u16x8, v);
  u ^= (u16)0x8000;
  return __builtin_bit_cast(bf16x8, u);
}
__device__ __forceinline__ float gelu_tanh(float x) {
  float t = tanhf(0.7978845608028654f * (x + 0.044715f * x * x * x));
  return 0.5f * x * (1.f + t);
}

// 16-lane (DPP row) reductions via row_ror — pure VALU, no ds_swizzle.
template <int CTRL>
__device__ __forceinline__ float dppror(float x) {
  const int xi = __builtin_bit_cast(int, x);
  return __builtin_bit_cast(float,
      __builtin_amdgcn_update_dpp(xi, xi, CTRL, 0xf, 0xf, false));
}
__device__ __forceinline__ float red16max(float x) {
  x = fmaxf(x, dppror<0x128>(x));  // ror:8
  x = fmaxf(x, dppror<0x124>(x));  // ror:4
  x = fmaxf(x, dppror<0x122>(x));  // ror:2
  x = fmaxf(x, dppror<0x121>(x));  // ror:1
  return x;
}
__device__ __forceinline__ float red16sum(float x) {
  x += dppror<0x128>(x);
  x += dppror<0x124>(x);
  x += dppror<0x122>(x);
  x += dppror<0x121>(x);
  return x;
}

// ---------------- weight fp32 -> bf16 ----------------
struct CJobs {
  const float* src[12];
  u16* dst[12];
  int blk_start[13];
};
__global__ __launch_bounds__(256) void convert_kernel(CJobs J) {
  const int blk = blockIdx.x;
  int jj = 0;
  while (jj < 11 && blk >= J.blk_start[jj + 1]) ++jj;
  const int idx = (blk - J.blk_start[jj]) * 256 + threadIdx.x;
  const float4 v = ((const float4*)J.src[jj])[idx];
  u16x4 o;
  o[0] = f2bf(v.x); o[1] = f2bf(v.y); o[2] = f2bf(v.z); o[3] = f2bf(v.w);
  *(u16x4*)(J.dst[jj] + (size_t)idx * 4) = o;
}

// ---------------- ada: m = clinear(silu(c)) ----------------
__global__ __launch_bounds__(256) void ada_kernel(
    const float* __restrict__ c_re, const float* __restrict__ c_im,
    const float* __restrict__ Wr, const float* __restrict__ Wi,
    const float* __restrict__ br, const float* __restrict__ bi,
    float* __restrict__ m_r, float* __restrict__ m_i) {
  __shared__ __align__(16) float sr[512], si[512];
  const int b = blockIdx.x / 12, nb = blockIdx.x % 12;
  const int tid = threadIdx.x;
  for (int i = tid; i < 512; i += 256) {
    const float xr = c_re[b * 512 + i], xi = c_im[b * 512 + i];
    sr[i] = xr / (1.f + __expf(-xr));
    si[i] = xi / (1.f + __expf(-xi));
  }
  __syncthreads();
  const int n = nb * 256 + tid;
  const float4* wr4 = (const float4*)(Wr + (size_t)n * 512);
  const float4* wi4 = (const float4*)(Wi + (size_t)n * 512);
  const float4* sr4 = (const float4*)sr;
  const float4* si4 = (const float4*)si;
  float ar = 0.f, ai = 0.f;
  for (int k = 0; k < 128; ++k) {
    const float4 a_ = sr4[k], b_ = si4[k], u = wr4[k], v = wi4[k];
    ar += a_.x * u.x - b_.x * v.x + a_.y * u.y - b_.y * v.y +
          a_.z * u.z - b_.z * v.z + a_.w * u.w - b_.w * v.w;
    ai += b_.x * u.x + a_.x * v.x + b_.y * u.y + a_.y * v.y +
          b_.z * u.z + a_.z * v.z + b_.w * u.w + a_.w * v.w;
  }
  m_r[(size_t)b * 3072 + n] = ar + br[n] - bi[n];
  m_i[(size_t)b * 3072 + n] = ai + br[n] + bi[n];
}

// ---------------- LN + modulate -> bf16 ----------------
__global__ __launch_bounds__(256) void ln_mod_kernel(
    const float* __restrict__ xr, const float* __restrict__ xi,
    const float* __restrict__ mv_r, const float* __restrict__ mv_i,
    int off_sh, int off_sc,
    u16* __restrict__ hr, u16* __restrict__ hi) {
  const int row = blockIdx.x;          // b*1024 + t
  const int b = row >> 10;
  const int tid = threadIdx.x;
  const float* xrp = xr + (size_t)row * 512;
  const float* xip = xi + (size_t)row * 512;
  const float r0 = xrp[tid], r1 = xrp[tid + 256];
  const float i0 = xip[tid], i1 = xip[tid + 256];
  float s0 = r0 + r1, s1 = r0 * r0 + r1 * r1;
  float s2 = i0 + i1, s3 = i0 * i0 + i1 * i1;
  #pragma unroll
  for (int o = 32; o > 0; o >>= 1) {
    s0 += __shfl_down(s0, o); s1 += __shfl_down(s1, o);
    s2 += __shfl_down(s2, o); s3 += __shfl_down(s3, o);
  }
  __shared__ float red[4][4];
  if ((tid & 63) == 0) {
    const int wv = tid >> 6;
    red[wv][0] = s0; red[wv][1] = s1; red[wv][2] = s2; red[wv][3] = s3;
  }
  __syncthreads();
  s0 = red[0][0] + red[1][0] + red[2][0] + red[3][0];
  s1 = red[0][1] + red[1][1] + red[2][1] + red[3][1];
  s2 = red[0][2] + red[1][2] + red[2][2] + red[3][2];
  s3 = red[0][3] + red[1][3] + red[2][3] + red[3][3];
  const float mr = s0 * (1.f / 512.f), mi = s2 * (1.f / 512.f);
  const float vr = s1 * (1.f / 512.f) - mr * mr;
  const float vi = s3 * (1.f / 512.f) - mi * mi;
  const float rr = rsqrtf(vr + 1e-6f), ri = rsqrtf(vi + 1e-6f);
  const float* shr = mv_r + (size_t)b * 3072 + off_sh;
  const float* shi = mv_i + (size_t)b * 3072 + off_sh;
  const float* scr = mv_r + (size_t)b * 3072 + off_sc;
  const float* sci = mv_i + (size_t)b * 3072 + off_sc;
  #pragma unroll
  for (int jj = 0; jj < 2; ++jj) {
    const int n = tid + jj * 256;
    const float nr = ((jj ? r1 : r0) - mr) * rr;
    const float ni = ((jj ? i1 : i0) - mi) * ri;
    const float a = 1.f + scr[n], bb = sci[n];
    hr[(size_t)row * 512 + n] = f2bf(nr * a - ni * bb + shr[n]);
    hi[(size_t)row * 512 + n] = f2bf(nr * bb + ni * a + shi[n]);
  }
}

// ---------------- complex GEMM: out = A @ W^T (+bias, +epilogue) -----------
// A: M x K bf16 row-major (lda=K). W: N x K bf16 row-major. M=4096 fixed grid.
// EPI: 0=QKV (3 segs, bf16 out, seg0 scaled 0.125*log2e, seg2 (V) stored
//      transposed [b*512+n][1024]), 1=O-proj (gate+resid fp32), 2=f1 (gelu,
//      bf16), 3=f2 (gate+resid -> d_out planes)
template <int EPI>
__global__ __launch_bounds__(256) void cgemm_kernel(
    const u16* __restrict__ Ar, const u16* __restrict__ Ai,
    const u16* __restrict__ W0r, const u16* __restrict__ W0i,
    const float* __restrict__ b0r, const float* __restrict__ b0i,
    const u16* __restrict__ W1r, const u16* __restrict__ W1i,
    const float* __restrict__ b1r, const float* __restrict__ b1i,
    const u16* __restrict__ W2r, const u16* __restrict__ W2i,
    const float* __restrict__ b2r, const float* __restrict__ b2i,
    int K, int ntiles_per_seg, int out_ld,
    u16* __restrict__ o0r, u16* __restrict__ o0i,
    u16* __restrict__ o1r, u16* __restrict__ o1i,
    u16* __restrict__ o2r, u16* __restrict__ o2i,
    const float* __restrict__ resid_r, const float* __restrict__ resid_i,
    const float* __restrict__ gate_r, const float* __restrict__ gate_i,
    float* __restrict__ ofr, float* __restrict__ ofi) {
  const int seg = blockIdx.y / ntiles_per_seg;
  const int n0 = (blockIdx.y % ntiles_per_seg) * 64;
  const int m0 = blockIdx.x * 64;
  const u16* Wr = (seg == 0) ? W0r : (seg == 1) ? W1r : W2r;
  const u16* Wi = (seg == 0) ? W0i : (seg == 1) ? W1i : W2i;
  const float* br = (seg == 0) ? b0r : (seg == 1) ? b1r : b2r;
  const float* bi = (seg == 0) ? b0i : (seg == 1) ? b1i : b2i;
  u16* obr = (seg == 0) ? o0r : (seg == 1) ? o1r : o2r;
  u16* obi = (seg == 0) ? o0i : (seg == 1) ? o1i : o2i;

  __shared__ __align__(16) u16 sA[2][64 * 72];
  __shared__ __align__(16) u16 sB[2][64 * 72];

  const int tid = threadIdx.x;
  const int w = tid >> 6, lane = tid & 63;
  const int wm = w >> 1, wn = w & 1;
  const int q4 = lane >> 4, c = lane & 15;

  const f32x4 z = {0.f, 0.f, 0.f, 0.f};
  f32x4 accR[2][2], accI[2][2];
  for (int a = 0; a < 2; ++a)
    for (int b2 = 0; b2 < 2; ++b2) { accR[a][b2] = z; accI[a][b2] = z; }

  for (int kt = 0; kt < K; kt += 64) {
    for (int idx = tid; idx < 512; idx += 256) {
      const int row = idx >> 3, cg = idx & 7;
      const int lo = row * 72 + cg * 8;
      *(u16x8*)&sA[0][lo] = *(const u16x8*)(Ar + (size_t)(m0 + row) * K + kt + cg * 8);
      *(u16x8*)&sA[1][lo] = *(const u16x8*)(Ai + (size_t)(m0 + row) * K + kt + cg * 8);
      *(u16x8*)&sB[0][lo] = *(const u16x8*)(Wr + (size_t)(n0 + row) * K + kt + cg * 8);
      *(u16x8*)&sB[1][lo] = *(const u16x8*)(Wi + (size_t)(n0 + row) * K + kt + cg * 8);
    }
    __syncthreads();
    #pragma unroll
    for (int kc = 0; kc < 2; ++kc) {
      bf16x8 a_r[2], a_i[2], a_n[2];
      #pragma unroll
      for (int mi = 0; mi < 2; ++mi) {
        const int off = (wm * 32 + mi * 16 + c) * 72 + kc * 32 + q4 * 8;
        a_r[mi] = ldsfrag(&sA[0][off]);
        a_i[mi] = ldsfrag(&sA[1][off]);
        a_n[mi] = negbf(a_i[mi]);
      }
      #pragma unroll
      for (int ni = 0; ni < 2; ++ni) {
        const int off = (wn * 32 + ni * 16 + c) * 72 + kc * 32 + q4 * 8;
        const bf16x8 b_r = ldsfrag(&sB[0][off]);
        const bf16x8 b_i = ldsfrag(&sB[1][off]);
        #pragma unroll
        for (int mi = 0; mi < 2; ++mi) {
          accR[mi][ni] = MFMA16(a_r[mi], b_r, accR[mi][ni]);
          accR[mi][ni] = MFMA16(a_n[mi], b_i, accR[mi][ni]);
          accI[mi][ni] = MFMA16(a_i[mi], b_r, accI[mi][ni]);
          accI[mi][ni] = MFMA16(a_r[mi], b_i, accI[mi][ni]);
        }
      }
    }
    __syncthreads();
  }

  // q scale folds 1/sqrt(DH) AND log2(e) (softmax runs in exp2 domain)
  const float scale = (EPI == 0 && seg == 0) ? 0.18033688011112042f : 1.f;
  #pragma unroll
  for (int mi = 0; mi < 2; ++mi)
    #pragma unroll
    for (int ni = 0; ni < 2; ++ni) {
      const int n = n0 + wn * 32 + ni * 16 + c;
      const float biasr = br[n] - bi[n];
      const float biasi = br[n] + bi[n];
      if (EPI == 0 && seg == 2) {
        // V: transposed store -> [b*512 + n][1024] at t.
        const int m = m0 + wm * 32 + mi * 16 + q4 * 4;
        u16x4 pr, pi;
        #pragma unroll
        for (int r = 0; r < 4; ++r) {
          pr[r] = f2bf(accR[mi][ni][r] + biasr);
          pi[r] = f2bf(accI[mi][ni][r] + biasi);
        }
        const size_t o = ((size_t)((m >> 10) * 512 + n)) * 1024 + (m & 1023);
        *(u16x4*)(obr + o) = pr;
        *(u16x4*)(obi + o) = pi;
        continue;
      }
      #pragma unroll
      for (int r = 0; r < 4; ++r) {
        const int m = m0 + wm * 32 + mi * 16 + q4 * 4 + r;
        const float ore = accR[mi][ni][r] + biasr;
        const float oim = accI[mi][ni][r] + biasi;
        if (EPI == 0) {
          obr[(size_t)m * out_ld + n] = f2bf(ore * scale);
          obi[(size_t)m * out_ld + n] = f2bf(oim * scale);
        } else if (EPI == 2) {
          obr[(size_t)m * out_ld + n] = f2bf(gelu_tanh(ore));
          obi[(size_t)m * out_ld + n] = f2bf(gelu_tanh(oim));
        } else {  // 1 or 3: gate + residual, fp32 out
          const int bb = m >> 10;
          const float gr = gate_r[(size_t)bb * 3072 + n];
          const float gi = gate_i[(size_t)bb * 3072 + n];
          const size_t o = (size_t)m * 512 + n;
          ofr[o] = resid_r[o] + ore * gr - oim * gi;
          ofi[o] = resid_i[o] + ore * gi + oim * gr;
        }
      }
    }
}

// ---------------- flash complex attention (barrier-free) ----------------
// grid (T/64, B*H); block 256 = 4 INDEPENDENT waves, 16 q-rows each.
// No __syncthreads in the k-loop: K and V^T fragments are read directly from
// global (L2-resident: 512 KB per (b,h), shared by 16 t-blocks). P repack
// goes through a per-wave private LDS region, guarded by lgkmcnt only.
// Q pre-scaled by 0.125*log2e; softmax in exp2 domain; DPP row reductions.
__global__ __launch_bounds__(256, 2) void attn_kernel(
    const u16* __restrict__ Qr, const u16* __restrict__ Qi,
    const u16* __restrict__ Kr, const u16* __restrict__ Ki,
    const u16* __restrict__ Vtr, const u16* __restrict__ Vti,
    u16* __restrict__ Or, u16* __restrict__ Oi) {
  __shared__ __align__(16) u16 sP[2][4][16 * 72];   // [plane][wave][row*72+k]

  const int tid = threadIdx.x;
  const int w = tid >> 6, lane = tid & 63;
  const int q4 = lane >> 4, c = lane & 15;
  const int bh = blockIdx.y, b = bh >> 3, h = bh & 7;
  const int t0 = blockIdx.x * 64;
  const size_t base = (size_t)b * Td * Dd + h * DHd;
  const size_t vbase = (size_t)bh << 16;            // bh * 64 * 1024

  // Q fragments direct from global (once)
  bf16x8 aQr[2], aQi[2], aQn[2];
  #pragma unroll
  for (int kc = 0; kc < 2; ++kc) {
    const size_t g = base + (size_t)(t0 + w * 16 + c) * Dd + kc * 32 + q4 * 8;
    aQr[kc] = gfrag(Qr + g);
    aQi[kc] = gfrag(Qi + g);
    aQn[kc] = negbf(aQi[kc]);
  }

  float mst[2][4], lst[2][4];
  #pragma unroll
  for (int p = 0; p < 2; ++p)
    for (int r = 0; r < 4; ++r) { mst[p][r] = -1e30f; lst[p][r] = 0.f; }
  const f32x4 z = {0.f, 0.f, 0.f, 0.f};
  f32x4 U1[4], U2[4], U3[4], U4[4];
  for (int i = 0; i < 4; ++i) { U1[i] = z; U2[i] = z; U3[i] = z; U4[i] = z; }

  u16* const pR = &sP[0][w][0];
  u16* const pI = &sP[1][w][0];

  for (int kt = 0; kt < 16; ++kt) {
    // ---- K fragments direct from global (16 x 16B loads) ----
    bf16x8 kR[4][2], kI[4][2];
    #pragma unroll
    for (int nb = 0; nb < 4; ++nb)
      #pragma unroll
      for (int kc = 0; kc < 2; ++kc) {
        const size_t g = base + (size_t)(kt * 64 + nb * 16 + c) * Dd + kc * 32 + q4 * 8;
        kR[nb][kc] = gfrag(Kr + g);
        kI[nb][kc] = gfrag(Ki + g);
      }

    // ---- QK^T ----
    f32x4 S[2][4];
    __builtin_amdgcn_s_setprio(1);
    #pragma unroll
    for (int nb = 0; nb < 4; ++nb) {
      f32x4 tr = z, ti = z;
      #pragma unroll
      for (int kc = 0; kc < 2; ++kc) {
        tr = MFMA16(aQr[kc], kR[nb][kc], tr);
        tr = MFMA16(aQn[kc], kI[nb][kc], tr);
        ti = MFMA16(aQi[kc], kR[nb][kc], ti);
        ti = MFMA16(aQr[kc], kI[nb][kc], ti);
      }
      S[0][nb] = tr; S[1][nb] = ti;
    }
    __builtin_amdgcn_s_setprio(0);

    // ---- V^T fragments: issue now, consumed after softmax (latency hidden) ----
    bf16x8 vR[4][2], vI[4][2];
    #pragma unroll
    for (int nd = 0; nd < 4; ++nd)
      #pragma unroll
      for (int kc = 0; kc < 2; ++kc) {
        const size_t gv = vbase + (size_t)(nd * 16 + c) * Td + kt * 64 + kc * 32 + q4 * 8;
        vR[nd][kc] = gfrag(Vtr + gv);
        vI[nd][kc] = gfrag(Vti + gv);
      }

    // ---- online softmax (exp2 domain, DPP reductions) ----
    float alpha[2][4];
    #pragma unroll
    for (int p = 0; p < 2; ++p) {
      u16* const pp = (p == 0) ? pR : pI;
      float rs[4];
      #pragma unroll
      for (int r = 0; r < 4; ++r) {
        float tm = fmaxf(fmaxf(S[p][0][r], S[p][1][r]), fmaxf(S[p][2][r], S[p][3][r]));
        tm = red16max(tm);
        const float mn = fmaxf(mst[p][r], tm);
        alpha[p][r] = exp2fast(mst[p][r] - mn);
        mst[p][r] = mn;
        rs[r] = 0.f;
      }
      #pragma unroll
      for (int nb = 0; nb < 4; ++nb)
        #pragma unroll
        for (int r = 0; r < 4; ++r) {
          const float pv = exp2fast(S[p][nb][r] - mst[p][r]);
          rs[r] += pv;
          pp[(q4 * 4 + r) * 72 + nb * 16 + c] = f2bf(pv);
        }
      #pragma unroll
      for (int r = 0; r < 4; ++r)
        lst[p][r] = lst[p][r] * alpha[p][r] + red16sum(rs[r]);
    }
    #pragma unroll
    for (int i = 0; i < 4; ++i)
      #pragma unroll
      for (int r = 0; r < 4; ++r) {
        U1[i][r] *= alpha[0][r]; U2[i][r] *= alpha[0][r];
        U3[i][r] *= alpha[1][r]; U4[i][r] *= alpha[1][r];
      }

    // ---- PV (P via own-wave LDS round-trip; V frags already in regs) ----
    asm volatile("s_waitcnt lgkmcnt(0)" ::: "memory");  // P stores drained
    __builtin_amdgcn_s_setprio(1);
    #pragma unroll
    for (int kc = 0; kc < 2; ++kc) {
      const int poff = c * 72 + kc * 32 + q4 * 8;
      const bf16x8 aPr = ldsfrag(pR + poff);
      const bf16x8 aPi = ldsfrag(pI + poff);
      #pragma unroll
      for (int nd = 0; nd < 4; ++nd) {
        U1[nd] = MFMA16(aPr, vR[nd][kc], U1[nd]);
        U2[nd] = MFMA16(aPr, vI[nd][kc], U2[nd]);
        U3[nd] = MFMA16(aPi, vR[nd][kc], U3[nd]);
        U4[nd] = MFMA16(aPi, vI[nd][kc], U4[nd]);
      }
    }
    __builtin_amdgcn_s_setprio(0);
  }

  #pragma unroll
  for (int nd = 0; nd < 4; ++nd)
    #pragma unroll
    for (int r = 0; r < 4; ++r) {
      const int trow = t0 + w * 16 + q4 * 4 + r;
      const int d = nd * 16 + c;
      const float ilre = 1.f / lst[0][r], ilim = 1.f / lst[1][r];
      const float ore = U1[nd][r] * ilre - U4[nd][r] * ilim;
      const float oim = U2[nd][r] * ilre + U3[nd][r] * ilim;
      const size_t g = base + (size_t)trow * Dd + d;
      Or[g] = f2bf(ore);
      Oi[g] = f2bf(oim);
    }
}

// ---------------------------------------------------------------------------
extern "C" void kernel_launch(void* const* d_in, const int* in_sizes, int n_in,
                              void* d_out, int out_size, void* d_ws, size_t ws_size,
                              hipStream_t stream) {
  const float* x_re  = (const float*)d_in[0];
  const float* x_im  = (const float*)d_in[1];
  const float* c_re  = (const float*)d_in[2];
  const float* c_im  = (const float*)d_in[3];
  const float* adaWr = (const float*)d_in[4];
  const float* adaWi = (const float*)d_in[5];
  const float* adabr = (const float*)d_in[6];
  const float* adabi = (const float*)d_in[7];
  const float* qWr = (const float*)d_in[8],  *qWi = (const float*)d_in[9];
  const float* qbr = (const float*)d_in[10], *qbi = (const float*)d_in[11];
  const float* kWr = (const float*)d_in[12], *kWi = (const float*)d_in[13];
  const float* kbr = (const float*)d_in[14], *kbi = (const float*)d_in[15];
  const float* vWr = (const float*)d_in[16], *vWi = (const float*)d_in[17];
  const float* vbr = (const float*)d_in[18], *vbi = (const float*)d_in[19];
  const float* oWr = (const float*)d_in[20], *oWi = (const float*)d_in[21];
  const float* obr = (const float*)d_in[22], *obi = (const float*)d_in[23];
  const float* f1Wr = (const float*)d_in[24], *f1Wi = (const float*)d_in[25];
  const float* f1br = (const float*)d_in[26], *f1bi = (const float*)d_in[27];
  const float* f2Wr = (const float*)d_in[28], *f2Wi = (const float*)d_in[29];
  const float* f2br = (const float*)d_in[30], *f2bi = (const float*)d_in[31];

  char* wsp = (char*)d_ws;
  size_t off = 0;
  auto alloc = [&](size_t bytes) -> void* {
    void* p = wsp + off;
    off += (bytes + 255) & ~(size_t)255;
    return p;
  };
  const size_t WQ = 512 * 512, WF = 2048 * 512;   // elements
  u16* wqr = (u16*)alloc(WQ * 2); u16* wqi = (u16*)alloc(WQ * 2);
  u16* wkr = (u16*)alloc(WQ * 2); u16* wki = (u16*)alloc(WQ * 2);
  u16* wvr = (u16*)alloc(WQ * 2); u16* wvi = (u16*)alloc(WQ * 2);
  u16* wor = (u16*)alloc(WQ * 2); u16* woi = (u16*)alloc(WQ * 2);
  u16* wf1r = (u16*)alloc(WF * 2); u16* wf1i = (u16*)alloc(WF * 2);
  u16* wf2r = (u16*)alloc(WF * 2); u16* wf2i = (u16*)alloc(WF * 2);
  float* m_r = (float*)alloc(4 * 3072 * 4);
  float* m_i = (float*)alloc(4 * 3072 * 4);
  const size_t ACT = (size_t)Bd * Td * Dd;        // 2,097,152 elements
  u16* h1r = (u16*)alloc(ACT * 2); u16* h1i = (u16*)alloc(ACT * 2);
  u16* qbr_ = (u16*)alloc(ACT * 2); u16* qbi_ = (u16*)alloc(ACT * 2);
  u16* kbr_ = (u16*)alloc(ACT * 2); u16* kbi_ = (u16*)alloc(ACT * 2);
  u16* vbr_ = (u16*)alloc(ACT * 2); u16* vbi_ = (u16*)alloc(ACT * 2);
  u16* atr = (u16*)alloc(ACT * 2); u16* ati = (u16*)alloc(ACT * 2);
  float* x2r = (float*)alloc(ACT * 4); float* x2i = (float*)alloc(ACT * 4);
  // aliases (dead buffers reused)
  u16* h2r = h1r; u16* h2i = h1i;                 // h1 dead after QKV
  u16* f1or = qbr_;                               // q..attn (32MB) dead after O-proj
  u16* f1oi = qbr_ + (size_t)Bd * Td * MLPd;

  // 1) weights -> bf16
  CJobs J;
  const float* wsrc[12] = {qWr, qWi, kWr, kWi, vWr, vWi, oWr, oWi, f1Wr, f1Wi, f2Wr, f2Wi};
  u16* wdst[12] = {wqr, wqi, wkr, wki, wvr, wvi, wor, woi, wf1r, wf1i, wf2r, wf2i};
  int cum = 0;
  for (int j = 0; j < 12; ++j) {
    J.src[j] = wsrc[j]; J.dst[j] = wdst[j]; J.blk_start[j] = cum;
    cum += (j < 8 ? (int)WQ : (int)WF) / 1024;
  }
  J.blk_start[12] = cum;  // 6144
  convert_kernel<<<cum, 256, 0, stream>>>(J);

  // 2) ada modulation vectors
  ada_kernel<<<48, 256, 0, stream>>>(c_re, c_im, adaWr, adaWi, adabr, adabi, m_r, m_i);

  // 3) LN1 + modulate(sh_a, sc_a)
  ln_mod_kernel<<<4096, 256, 0, stream>>>(x_re, x_im, m_r, m_i, 0, 512, h1r, h1i);

  // 4) QKV (q scaled by 0.125*log2e; V stored transposed [bh][d][t])
  cgemm_kernel<0><<<dim3(64, 24), 256, 0, stream>>>(
      h1r, h1i, wqr, wqi, qbr, qbi, wkr, wki, kbr, kbi, wvr, wvi, vbr, vbi,
      512, 8, 512, qbr_, qbi_, kbr_, kbi_, vbr_, vbi_,
      nullptr, nullptr, nullptr, nullptr, nullptr, nullptr);

  // 5) attention (V^T layout input)
  attn_kernel<<<dim3(16, 32), 256, 0, stream>>>(qbr_, qbi_, kbr_, kbi_, vbr_, vbi_, atr, ati);

  // 6) O-proj + gate_a + residual -> x2 (fp32)
  cgemm_kernel<1><<<dim3(64, 8), 256, 0, stream>>>(
      atr, ati, wor, woi, obr, obi, wor, woi, obr, obi, wor, woi, obr, obi,
      512, 8, 512, nullptr, nullptr, nullptr, nullptr, nullptr, nullptr,
      x_re, x_im, m_r + 1024, m_i + 1024, x2r, x2i);

  // 7) LN2 + modulate(sh_m, sc_m)
  ln_mod_kernel<<<4096, 256, 0, stream>>>(x2r, x2i, m_r, m_i, 1536, 2048, h2r, h2i);

  // 8) f1 + gelu
  cgemm_kernel<2><<<dim3(64, 32), 256, 0, stream>>>(
      h2r, h2i, wf1r, wf1i, f1br, f1bi, wf1r, wf1i, f1br, f1bi, wf1r, wf1i, f1br, f1bi,
      512, 32, 2048, f1or, f1oi, nullptr, nullptr, nullptr, nullptr,
      nullptr, nullptr, nullptr, nullptr, nullptr, nullptr);

  // 9) f2 + gate_m + residual -> d_out (2 planes)
  float* outp = (float*)d_out;
  cgemm_kernel<3><<<dim3(64, 8), 256, 0, stream>>>(
      f1or, f1oi, wf2r, wf2i, f2br, f2bi, wf2r, wf2i, f2br, f2bi, wf2r, wf2i, f2br, f2bi,
      2048, 8, 512, nullptr, nullptr, nullptr, nullptr, nullptr, nullptr,
      x2r, x2i, m_r + 2560, m_i + 2560, outp, outp + ACT);
}

// Round 4
// 427.886 us; speedup vs baseline: 1.1171x; 1.1171x over previous
//
#include <hip/hip_runtime.h>

// ---------------------------------------------------------------------------
// CDiTBlock: complex DiT block on MI355X.
// Stages: convert weights->bf16 | ada (silu+clinear, fp32) | LN1+mod ->bf16
//         QKV cgemm (q pre-scaled 0.125*log2e, V written TRANSPOSED [bh][d][t])
//         flash complex attention (global_load_lds double-buffered K/V tiles,
//             ONE barrier/tile, XOR-swizzled LDS, private-P, DPP reduce,
//             exp2-domain softmax)
//         O-proj cgemm (+gate_a,+x residual, fp32) | LN2+mod ->bf16
//         f1 cgemm (+tanh-gelu) | f2 cgemm (+gate_m,+x2 residual -> d_out)
// All matmuls: bf16 MFMA 16x16x32, fp32 accum. GEMM tiles 64x64, BK=64.
// Staging everywhere: global_load_lds width=16, source-side XOR swizzle
// (chunk j fetched = j ^ (row&7)) + matching swizzle on ds_read offsets
// -> linear LDS [64][64], fragment reads 2-way-conflict (free).
// ---------------------------------------------------------------------------

typedef unsigned short u16;
typedef __attribute__((ext_vector_type(8))) __bf16 bf16x8;
typedef __attribute__((ext_vector_type(8))) u16    u16x8;
typedef __attribute__((ext_vector_type(4))) u16    u16x4;
typedef __attribute__((ext_vector_type(4))) float  f32x4;

#define MFMA16(a, b, c) __builtin_amdgcn_mfma_f32_16x16x32_bf16(a, b, c, 0, 0, 0)

static constexpr int Bd = 4, Td = 1024, Dd = 512, Hd = 8, DHd = 64, MLPd = 2048;

__device__ __forceinline__ u16 f2bf(float x) {
  return __builtin_bit_cast(u16, (__bf16)x);
}
__device__ __forceinline__ float exp2fast(float x) {
  return __builtin_amdgcn_exp2f(x);   // v_exp_f32: D = 2^S0
}
__device__ __forceinline__ bf16x8 ldsfrag(const u16* p) {
  return __builtin_bit_cast(bf16x8, *(const u16x8*)p);
}
__device__ __forceinline__ bf16x8 gfrag(const u16* p) {
  return __builtin_bit_cast(bf16x8, *(const u16x8*)p);
}
__device__ __forceinline__ bf16x8 negbf(bf16x8 v) {
  u16x8 u = __builtin_bit_cast(u16x8, v);
  u ^= (u16)0x8000;
  return __builtin_bit_cast(bf16x8, u);
}
__device__ __forceinline__ float gelu_tanh(float x) {
  float t = tanhf(0.7978845608028654f * (x + 0.044715f * x * x * x));
  return 0.5f * x * (1.f + t);
}
// async global->LDS, 16B per lane; LDS dest = wave-uniform base + lane*16
__device__ __forceinline__ void gll16(const u16* g, u16* l) {
  __builtin_amdgcn_global_load_lds(
      (const __attribute__((address_space(1))) unsigned int*)g,
      (__attribute__((address_space(3))) unsigned int*)l, 16, 0, 0);
}

// 16-lane (DPP row) reductions via row_ror — pure VALU, no ds_swizzle.
template <int CTRL>
__device__ __forceinline__ float dppror(float x) {
  const int xi = __builtin_bit_cast(int, x);
  return __builtin_bit_cast(float,
      __builtin_amdgcn_update_dpp(xi, xi, CTRL, 0xf, 0xf, false));
}
__device__ __forceinline__ float red16max(float x) {
  x = fmaxf(x, dppror<0x128>(x));  // ror:8
  x = fmaxf(x, dppror<0x124>(x));  // ror:4
  x = fmaxf(x, dppror<0x122>(x));  // ror:2
  x = fmaxf(x, dppror<0x121>(x));  // ror:1
  return x;
}
__device__ __forceinline__ float red16sum(float x) {
  x += dppror<0x128>(x);
  x += dppror<0x124>(x);
  x += dppror<0x122>(x);
  x += dppror<0x121>(x);
  return x;
}

// ---------------- weight fp32 -> bf16 ----------------
struct CJobs {
  const float* src[12];
  u16* dst[12];
  int blk_start[13];
};
__global__ __launch_bounds__(256) void convert_kernel(CJobs J) {
  const int blk = blockIdx.x;
  int jj = 0;
  while (jj < 11 && blk >= J.blk_start[jj + 1]) ++jj;
  const int idx = (blk - J.blk_start[jj]) * 256 + threadIdx.x;
  const float4 v = ((const float4*)J.src[jj])[idx];
  u16x4 o;
  o[0] = f2bf(v.x); o[1] = f2bf(v.y); o[2] = f2bf(v.z); o[3] = f2bf(v.w);
  *(u16x4*)(J.dst[jj] + (size_t)idx * 4) = o;
}

// ---------------- ada: m = clinear(silu(c)) ----------------
__global__ __launch_bounds__(256) void ada_kernel(
    const float* __restrict__ c_re, const float* __restrict__ c_im,
    const float* __restrict__ Wr, const float* __restrict__ Wi,
    const float* __restrict__ br, const float* __restrict__ bi,
    float* __restrict__ m_r, float* __restrict__ m_i) {
  __shared__ __align__(16) float sr[512], si[512];
  const int b = blockIdx.x / 12, nb = blockIdx.x % 12;
  const int tid = threadIdx.x;
  for (int i = tid; i < 512; i += 256) {
    const float xr = c_re[b * 512 + i], xi = c_im[b * 512 + i];
    sr[i] = xr / (1.f + __expf(-xr));
    si[i] = xi / (1.f + __expf(-xi));
  }
  __syncthreads();
  const int n = nb * 256 + tid;
  const float4* wr4 = (const float4*)(Wr + (size_t)n * 512);
  const float4* wi4 = (const float4*)(Wi + (size_t)n * 512);
  const float4* sr4 = (const float4*)sr;
  const float4* si4 = (const float4*)si;
  float ar = 0.f, ai = 0.f;
  for (int k = 0; k < 128; ++k) {
    const float4 a_ = sr4[k], b_ = si4[k], u = wr4[k], v = wi4[k];
    ar += a_.x * u.x - b_.x * v.x + a_.y * u.y - b_.y * v.y +
          a_.z * u.z - b_.z * v.z + a_.w * u.w - b_.w * v.w;
    ai += b_.x * u.x + a_.x * v.x + b_.y * u.y + a_.y * v.y +
          b_.z * u.z + a_.z * v.z + b_.w * u.w + a_.w * v.w;
  }
  m_r[(size_t)b * 3072 + n] = ar + br[n] - bi[n];
  m_i[(size_t)b * 3072 + n] = ai + br[n] + bi[n];
}

// ---------------- LN + modulate -> bf16 ----------------
__global__ __launch_bounds__(256) void ln_mod_kernel(
    const float* __restrict__ xr, const float* __restrict__ xi,
    const float* __restrict__ mv_r, const float* __restrict__ mv_i,
    int off_sh, int off_sc,
    u16* __restrict__ hr, u16* __restrict__ hi) {
  const int row = blockIdx.x;          // b*1024 + t
  const int b = row >> 10;
  const int tid = threadIdx.x;
  const float* xrp = xr + (size_t)row * 512;
  const float* xip = xi + (size_t)row * 512;
  const float r0 = xrp[tid], r1 = xrp[tid + 256];
  const float i0 = xip[tid], i1 = xip[tid + 256];
  float s0 = r0 + r1, s1 = r0 * r0 + r1 * r1;
  float s2 = i0 + i1, s3 = i0 * i0 + i1 * i1;
  #pragma unroll
  for (int o = 32; o > 0; o >>= 1) {
    s0 += __shfl_down(s0, o); s1 += __shfl_down(s1, o);
    s2 += __shfl_down(s2, o); s3 += __shfl_down(s3, o);
  }
  __shared__ float red[4][4];
  if ((tid & 63) == 0) {
    const int wv = tid >> 6;
    red[wv][0] = s0; red[wv][1] = s1; red[wv][2] = s2; red[wv][3] = s3;
  }
  __syncthreads();
  s0 = red[0][0] + red[1][0] + red[2][0] + red[3][0];
  s1 = red[0][1] + red[1][1] + red[2][1] + red[3][1];
  s2 = red[0][2] + red[1][2] + red[2][2] + red[3][2];
  s3 = red[0][3] + red[1][3] + red[2][3] + red[3][3];
  const float mr = s0 * (1.f / 512.f), mi = s2 * (1.f / 512.f);
  const float vr = s1 * (1.f / 512.f) - mr * mr;
  const float vi = s3 * (1.f / 512.f) - mi * mi;
  const float rr = rsqrtf(vr + 1e-6f), ri = rsqrtf(vi + 1e-6f);
  const float* shr = mv_r + (size_t)b * 3072 + off_sh;
  const float* shi = mv_i + (size_t)b * 3072 + off_sh;
  const float* scr = mv_r + (size_t)b * 3072 + off_sc;
  const float* sci = mv_i + (size_t)b * 3072 + off_sc;
  #pragma unroll
  for (int jj = 0; jj < 2; ++jj) {
    const int n = tid + jj * 256;
    const float nr = ((jj ? r1 : r0) - mr) * rr;
    const float ni = ((jj ? i1 : i0) - mi) * ri;
    const float a = 1.f + scr[n], bb = sci[n];
    hr[(size_t)row * 512 + n] = f2bf(nr * a - ni * bb + shr[n]);
    hi[(size_t)row * 512 + n] = f2bf(nr * bb + ni * a + shi[n]);
  }
}

// ---------------- complex GEMM: out = A @ W^T (+bias, +epilogue) -----------
// A: M x K bf16 row-major (lda=K). W: N x K bf16 row-major. M=4096 fixed grid.
// Staging via global_load_lds with source-side XOR swizzle; LDS [64][64].
// EPI: 0=QKV (3 segs, bf16 out, seg0 scaled 0.125*log2e, seg2 (V) stored
//      transposed [b*512+n][1024]), 1=O-proj (gate+resid fp32), 2=f1 (gelu,
//      bf16), 3=f2 (gate+resid -> d_out planes)
template <int EPI>
__global__ __launch_bounds__(256) void cgemm_kernel(
    const u16* __restrict__ Ar, const u16* __restrict__ Ai,
    const u16* __restrict__ W0r, const u16* __restrict__ W0i,
    const float* __restrict__ b0r, const float* __restrict__ b0i,
    const u16* __restrict__ W1r, const u16* __restrict__ W1i,
    const float* __restrict__ b1r, const float* __restrict__ b1i,
    const u16* __restrict__ W2r, const u16* __restrict__ W2i,
    const float* __restrict__ b2r, const float* __restrict__ b2i,
    int K, int ntiles_per_seg, int out_ld,
    u16* __restrict__ o0r, u16* __restrict__ o0i,
    u16* __restrict__ o1r, u16* __restrict__ o1i,
    u16* __restrict__ o2r, u16* __restrict__ o2i,
    const float* __restrict__ resid_r, const float* __restrict__ resid_i,
    const float* __restrict__ gate_r, const float* __restrict__ gate_i,
    float* __restrict__ ofr, float* __restrict__ ofi) {
  const int seg = blockIdx.y / ntiles_per_seg;
  const int n0 = (blockIdx.y % ntiles_per_seg) * 64;
  const int m0 = blockIdx.x * 64;
  const u16* Wr = (seg == 0) ? W0r : (seg == 1) ? W1r : W2r;
  const u16* Wi = (seg == 0) ? W0i : (seg == 1) ? W1i : W2i;
  const float* br = (seg == 0) ? b0r : (seg == 1) ? b1r : b2r;
  const float* bi = (seg == 0) ? b0i : (seg == 1) ? b1i : b2i;
  u16* obr = (seg == 0) ? o0r : (seg == 1) ? o1r : o2r;
  u16* obi = (seg == 0) ? o0i : (seg == 1) ? o1i : o2i;

  __shared__ __align__(16) u16 sA[2][64 * 64];
  __shared__ __align__(16) u16 sB[2][64 * 64];

  const int tid = threadIdx.x;
  const int w = tid >> 6, lane = tid & 63;
  const int wm = w >> 1, wn = w & 1;
  const int q4 = lane >> 4, c = lane & 15;
  // staging coords: lane covers row r8 (0..7) of an 8-row chunk; fetches
  // swizzled 16B chunk jsw so that storage[(r,j)] = global[(r, j^(r&7))].
  const int r8 = lane >> 3, jsw = (lane & 7) ^ r8;
  const int c7 = c & 7;

  const f32x4 z = {0.f, 0.f, 0.f, 0.f};
  f32x4 accR[2][2], accI[2][2];
  for (int a = 0; a < 2; ++a)
    for (int b2 = 0; b2 < 2; ++b2) { accR[a][b2] = z; accI[a][b2] = z; }

  for (int kt = 0; kt < K; kt += 64) {
    #pragma unroll
    for (int half = 0; half < 2; ++half) {
      const int rr = w * 16 + half * 8;          // wave-uniform base row
      const size_t ga = (size_t)(m0 + rr + r8) * K + kt + jsw * 8;
      gll16(Ar + ga, &sA[0][rr * 64]);
      gll16(Ai + ga, &sA[1][rr * 64]);
      const size_t gb = (size_t)(n0 + rr + r8) * K + kt + jsw * 8;
      gll16(Wr + gb, &sB[0][rr * 64]);
      gll16(Wi + gb, &sB[1][rr * 64]);
    }
    __syncthreads();   // drains vmcnt (gll) + joins waves
    #pragma unroll
    for (int kc = 0; kc < 2; ++kc) {
      bf16x8 a_r[2], a_i[2], a_n[2];
      #pragma unroll
      for (int mi = 0; mi < 2; ++mi) {
        const int off = (wm * 32 + mi * 16 + c) * 64 + (((kc * 4 + q4) ^ c7) * 8);
        a_r[mi] = ldsfrag(&sA[0][off]);
        a_i[mi] = ldsfrag(&sA[1][off]);
        a_n[mi] = negbf(a_i[mi]);
      }
      #pragma unroll
      for (int ni = 0; ni < 2; ++ni) {
        const int off = (wn * 32 + ni * 16 + c) * 64 + (((kc * 4 + q4) ^ c7) * 8);
        const bf16x8 b_r = ldsfrag(&sB[0][off]);
        const bf16x8 b_i = ldsfrag(&sB[1][off]);
        #pragma unroll
        for (int mi = 0; mi < 2; ++mi) {
          accR[mi][ni] = MFMA16(a_r[mi], b_r, accR[mi][ni]);
          accR[mi][ni] = MFMA16(a_n[mi], b_i, accR[mi][ni]);
          accI[mi][ni] = MFMA16(a_i[mi], b_r, accI[mi][ni]);
          accI[mi][ni] = MFMA16(a_r[mi], b_i, accI[mi][ni]);
        }
      }
    }
    __syncthreads();
  }

  // q scale folds 1/sqrt(DH) AND log2(e) (softmax runs in exp2 domain)
  const float scale = (EPI == 0 && seg == 0) ? 0.18033688011112042f : 1.f;
  #pragma unroll
  for (int mi = 0; mi < 2; ++mi)
    #pragma unroll
    for (int ni = 0; ni < 2; ++ni) {
      const int n = n0 + wn * 32 + ni * 16 + c;
      const float biasr = br[n] - bi[n];
      const float biasi = br[n] + bi[n];
      if (EPI == 0 && seg == 2) {
        // V: transposed store -> [b*512 + n][1024] at t.
        const int m = m0 + wm * 32 + mi * 16 + q4 * 4;
        u16x4 pr, pi;
        #pragma unroll
        for (int r = 0; r < 4; ++r) {
          pr[r] = f2bf(accR[mi][ni][r] + biasr);
          pi[r] = f2bf(accI[mi][ni][r] + biasi);
        }
        const size_t o = ((size_t)((m >> 10) * 512 + n)) * 1024 + (m & 1023);
        *(u16x4*)(obr + o) = pr;
        *(u16x4*)(obi + o) = pi;
        continue;
      }
      #pragma unroll
      for (int r = 0; r < 4; ++r) {
        const int m = m0 + wm * 32 + mi * 16 + q4 * 4 + r;
        const float ore = accR[mi][ni][r] + biasr;
        const float oim = accI[mi][ni][r] + biasi;
        if (EPI == 0) {
          obr[(size_t)m * out_ld + n] = f2bf(ore * scale);
          obi[(size_t)m * out_ld + n] = f2bf(oim * scale);
        } else if (EPI == 2) {
          obr[(size_t)m * out_ld + n] = f2bf(gelu_tanh(ore));
          obi[(size_t)m * out_ld + n] = f2bf(gelu_tanh(oim));
        } else {  // 1 or 3: gate + residual, fp32 out
          const int bb = m >> 10;
          const float gr = gate_r[(size_t)bb * 3072 + n];
          const float gi = gate_i[(size_t)bb * 3072 + n];
          const size_t o = (size_t)m * 512 + n;
          ofr[o] = resid_r[o] + ore * gr - oim * gi;
          ofi[o] = resid_i[o] + ore * gi + oim * gr;
        }
      }
    }
}

// ---------------- flash complex attention ----------------
// grid (T/64, B*H); block 256 (4 waves, 16 q-rows each). Q pre-scaled.
// K/V^T tiles staged via global_load_lds into double-buffered swizzled LDS,
// prefetched one full tile ahead; ONE barrier per k-tile. P via per-wave
// private LDS (lgkmcnt-guarded). exp2-domain softmax, DPP reductions.
__global__ __launch_bounds__(256, 2) void attn_kernel(
    const u16* __restrict__ Qr, const u16* __restrict__ Qi,
    const u16* __restrict__ Kr, const u16* __restrict__ Ki,
    const u16* __restrict__ Vtr, const u16* __restrict__ Vti,
    u16* __restrict__ Or, u16* __restrict__ Oi) {
  __shared__ __align__(16) u16 sK[2][2][64 * 64];   // [buf][plane][row*64+col]
  __shared__ __align__(16) u16 sV[2][2][64 * 64];   // V^T: row=d, col=token
  __shared__ __align__(16) u16 sP[2][4][16 * 72];   // [plane][wave][row*72+k]

  const int tid = threadIdx.x;
  const int w = tid >> 6, lane = tid & 63;
  const int q4 = lane >> 4, c = lane & 15;
  const int c7 = c & 7;
  const int bh = blockIdx.y, b = bh >> 3, h = bh & 7;
  const int t0 = blockIdx.x * 64;
  const size_t base = (size_t)b * Td * Dd + h * DHd;
  const size_t vbase = (size_t)bh << 16;            // bh * 64 * 1024
  const int r8 = lane >> 3, jsw = (lane & 7) ^ r8;

  // Q fragments direct from global (once)
  bf16x8 aQr[2], aQi[2], aQn[2];
  #pragma unroll
  for (int kc = 0; kc < 2; ++kc) {
    const size_t g = base + (size_t)(t0 + w * 16 + c) * Dd + kc * 32 + q4 * 8;
    aQr[kc] = gfrag(Qr + g);
    aQi[kc] = gfrag(Qi + g);
    aQn[kc] = negbf(aQi[kc]);
  }

  float mst[2][4], lst[2][4];
  #pragma unroll
  for (int p = 0; p < 2; ++p)
    for (int r = 0; r < 4; ++r) { mst[p][r] = -1e30f; lst[p][r] = 0.f; }
  const f32x4 z = {0.f, 0.f, 0.f, 0.f};
  f32x4 U1[4], U2[4], U3[4], U4[4];
  for (int i = 0; i < 4; ++i) { U1[i] = z; U2[i] = z; U3[i] = z; U4[i] = z; }

  u16* const pR = &sP[0][w][0];
  u16* const pI = &sP[1][w][0];

  auto stage = [&](int kt, int bi) {
    #pragma unroll
    for (int half = 0; half < 2; ++half) {
      const int rr = w * 16 + half * 8;             // wave-uniform base row
      const size_t gk = base + (size_t)(kt * 64 + rr + r8) * Dd + jsw * 8;
      gll16(Kr + gk, &sK[bi][0][rr * 64]);
      gll16(Ki + gk, &sK[bi][1][rr * 64]);
      const size_t gv = vbase + (size_t)(rr + r8) * Td + kt * 64 + jsw * 8;
      gll16(Vtr + gv, &sV[bi][0][rr * 64]);
      gll16(Vti + gv, &sV[bi][1][rr * 64]);
    }
  };

  stage(0, 0);

  for (int kt = 0; kt < 16; ++kt) {
    __syncthreads();                 // drains gll for buf[kt&1]; joins waves
    if (kt < 15) stage(kt + 1, (kt + 1) & 1);   // async prefetch, other buffer
    const int bi = kt & 1;

    // ---- QK^T ----
    f32x4 S[2][4];
    __builtin_amdgcn_s_setprio(1);
    #pragma unroll
    for (int nb = 0; nb < 4; ++nb) {
      f32x4 tr = z, ti = z;
      #pragma unroll
      for (int kc = 0; kc < 2; ++kc) {
        const int off = (nb * 16 + c) * 64 + (((kc * 4 + q4) ^ c7) * 8);
        const bf16x8 bKr = ldsfrag(&sK[bi][0][off]);
        const bf16x8 bKi = ldsfrag(&sK[bi][1][off]);
        tr = MFMA16(aQr[kc], bKr, tr);
        tr = MFMA16(aQn[kc], bKi, tr);
        ti = MFMA16(aQi[kc], bKr, ti);
        ti = MFMA16(aQr[kc], bKi, ti);
      }
      S[0][nb] = tr; S[1][nb] = ti;
    }
    __builtin_amdgcn_s_setprio(0);

    // ---- online softmax (exp2 domain, DPP reductions) ----
    float alpha[2][4];
    #pragma unroll
    for (int p = 0; p < 2; ++p) {
      u16* const pp = (p == 0) ? pR : pI;
      float rs[4];
      #pragma unroll
      for (int r = 0; r < 4; ++r) {
        float tm = fmaxf(fmaxf(S[p][0][r], S[p][1][r]), fmaxf(S[p][2][r], S[p][3][r]));
        tm = red16max(tm);
        const float mn = fmaxf(mst[p][r], tm);
        alpha[p][r] = exp2fast(mst[p][r] - mn);
        mst[p][r] = mn;
        rs[r] = 0.f;
      }
      #pragma unroll
      for (int nb = 0; nb < 4; ++nb)
        #pragma unroll
        for (int r = 0; r < 4; ++r) {
          const float pv = exp2fast(S[p][nb][r] - mst[p][r]);
          rs[r] += pv;
          pp[(q4 * 4 + r) * 72 + nb * 16 + c] = f2bf(pv);
        }
      #pragma unroll
      for (int r = 0; r < 4; ++r)
        lst[p][r] = lst[p][r] * alpha[p][r] + red16sum(rs[r]);
    }
    #pragma unroll
    for (int i = 0; i < 4; ++i)
      #pragma unroll
      for (int r = 0; r < 4; ++r) {
        U1[i][r] *= alpha[0][r]; U2[i][r] *= alpha[0][r];
        U3[i][r] *= alpha[1][r]; U4[i][r] *= alpha[1][r];
      }

    // ---- PV (P via own-wave LDS round-trip; V from swizzled LDS) ----
    asm volatile("s_waitcnt lgkmcnt(0)" ::: "memory");  // P stores drained
    __builtin_amdgcn_s_setprio(1);
    #pragma unroll
    for (int kc = 0; kc < 2; ++kc) {
      const int poff = c * 72 + kc * 32 + q4 * 8;
      const bf16x8 aPr = ldsfrag(pR + poff);
      const bf16x8 aPi = ldsfrag(pI + poff);
      #pragma unroll
      for (int nd = 0; nd < 4; ++nd) {
        const int voff = (nd * 16 + c) * 64 + (((kc * 4 + q4) ^ c7) * 8);
        const bf16x8 bVr = ldsfrag(&sV[bi][0][voff]);
        const bf16x8 bVi = ldsfrag(&sV[bi][1][voff]);
        U1[nd] = MFMA16(aPr, bVr, U1[nd]);
        U2[nd] = MFMA16(aPr, bVi, U2[nd]);
        U3[nd] = MFMA16(aPi, bVr, U3[nd]);
        U4[nd] = MFMA16(aPi, bVi, U4[nd]);
      }
    }
    __builtin_amdgcn_s_setprio(0);
  }

  #pragma unroll
  for (int nd = 0; nd < 4; ++nd)
    #pragma unroll
    for (int r = 0; r < 4; ++r) {
      const int trow = t0 + w * 16 + q4 * 4 + r;
      const int d = nd * 16 + c;
      const float ilre = 1.f / lst[0][r], ilim = 1.f / lst[1][r];
      const float ore = U1[nd][r] * ilre - U4[nd][r] * ilim;
      const float oim = U2[nd][r] * ilre + U3[nd][r] * ilim;
      const size_t g = base + (size_t)trow * Dd + d;
      Or[g] = f2bf(ore);
      Oi[g] = f2bf(oim);
    }
}

// ---------------------------------------------------------------------------
extern "C" void kernel_launch(void* const* d_in, const int* in_sizes, int n_in,
                              void* d_out, int out_size, void* d_ws, size_t ws_size,
                              hipStream_t stream) {
  const float* x_re  = (const float*)d_in[0];
  const float* x_im  = (const float*)d_in[1];
  const float* c_re  = (const float*)d_in[2];
  const float* c_im  = (const float*)d_in[3];
  const float* adaWr = (const float*)d_in[4];
  const float* adaWi = (const float*)d_in[5];
  const float* adabr = (const float*)d_in[6];
  const float* adabi = (const float*)d_in[7];
  const float* qWr = (const float*)d_in[8],  *qWi = (const float*)d_in[9];
  const float* qbr = (const float*)d_in[10], *qbi = (const float*)d_in[11];
  const float* kWr = (const float*)d_in[12], *kWi = (const float*)d_in[13];
  const float* kbr = (const float*)d_in[14], *kbi = (const float*)d_in[15];
  const float* vWr = (const float*)d_in[16], *vWi = (const float*)d_in[17];
  const float* vbr = (const float*)d_in[18], *vbi = (const float*)d_in[19];
  const float* oWr = (const float*)d_in[20], *oWi = (const float*)d_in[21];
  const float* obr = (const float*)d_in[22], *obi = (const float*)d_in[23];
  const float* f1Wr = (const float*)d_in[24], *f1Wi = (const float*)d_in[25];
  const float* f1br = (const float*)d_in[26], *f1bi = (const float*)d_in[27];
  const float* f2Wr = (const float*)d_in[28], *f2Wi = (const float*)d_in[29];
  const float* f2br = (const float*)d_in[30], *f2bi = (const float*)d_in[31];

  char* wsp = (char*)d_ws;
  size_t off = 0;
  auto alloc = [&](size_t bytes) -> void* {
    void* p = wsp + off;
    off += (bytes + 255) & ~(size_t)255;
    return p;
  };
  const size_t WQ = 512 * 512, WF = 2048 * 512;   // elements
  u16* wqr = (u16*)alloc(WQ * 2); u16* wqi = (u16*)alloc(WQ * 2);
  u16* wkr = (u16*)alloc(WQ * 2); u16* wki = (u16*)alloc(WQ * 2);
  u16* wvr = (u16*)alloc(WQ * 2); u16* wvi = (u16*)alloc(WQ * 2);
  u16* wor = (u16*)alloc(WQ * 2); u16* woi = (u16*)alloc(WQ * 2);
  u16* wf1r = (u16*)alloc(WF * 2); u16* wf1i = (u16*)alloc(WF * 2);
  u16* wf2r = (u16*)alloc(WF * 2); u16* wf2i = (u16*)alloc(WF * 2);
  float* m_r = (float*)alloc(4 * 3072 * 4);
  float* m_i = (float*)alloc(4 * 3072 * 4);
  const size_t ACT = (size_t)Bd * Td * Dd;        // 2,097,152 elements
  u16* h1r = (u16*)alloc(ACT * 2); u16* h1i = (u16*)alloc(ACT * 2);
  u16* qbr_ = (u16*)alloc(ACT * 2); u16* qbi_ = (u16*)alloc(ACT * 2);
  u16* kbr_ = (u16*)alloc(ACT * 2); u16* kbi_ = (u16*)alloc(ACT * 2);
  u16* vbr_ = (u16*)alloc(ACT * 2); u16* vbi_ = (u16*)alloc(ACT * 2);
  u16* atr = (u16*)alloc(ACT * 2); u16* ati = (u16*)alloc(ACT * 2);
  float* x2r = (float*)alloc(ACT * 4); float* x2i = (float*)alloc(ACT * 4);
  // aliases (dead buffers reused)
  u16* h2r = h1r; u16* h2i = h1i;                 // h1 dead after QKV
  u16* f1or = qbr_;                               // q..attn (32MB) dead after O-proj
  u16* f1oi = qbr_ + (size_t)Bd * Td * MLPd;

  // 1) weights -> bf16
  CJobs J;
  const float* wsrc[12] = {qWr, qWi, kWr, kWi, vWr, vWi, oWr, oWi, f1Wr, f1Wi, f2Wr, f2Wi};
  u16* wdst[12] = {wqr, wqi, wkr, wki, wvr, wvi, wor, woi, wf1r, wf1i, wf2r, wf2i};
  int cum = 0;
  for (int j = 0; j < 12; ++j) {
    J.src[j] = wsrc[j]; J.dst[j] = wdst[j]; J.blk_start[j] = cum;
    cum += (j < 8 ? (int)WQ : (int)WF) / 1024;
  }
  J.blk_start[12] = cum;  // 6144
  convert_kernel<<<cum, 256, 0, stream>>>(J);

  // 2) ada modulation vectors
  ada_kernel<<<48, 256, 0, stream>>>(c_re, c_im, adaWr, adaWi, adabr, adabi, m_r, m_i);

  // 3) LN1 + modulate(sh_a, sc_a)
  ln_mod_kernel<<<4096, 256, 0, stream>>>(x_re, x_im, m_r, m_i, 0, 512, h1r, h1i);

  // 4) QKV (q scaled by 0.125*log2e; V stored transposed [bh][d][t])
  cgemm_kernel<0><<<dim3(64, 24), 256, 0, stream>>>(
      h1r, h1i, wqr, wqi, qbr, qbi, wkr, wki, kbr, kbi, wvr, wvi, vbr, vbi,
      512, 8, 512, qbr_, qbi_, kbr_, kbi_, vbr_, vbi_,
      nullptr, nullptr, nullptr, nullptr, nullptr, nullptr);

  // 5) attention (V^T layout input)
  attn_kernel<<<dim3(16, 32), 256, 0, stream>>>(qbr_, qbi_, kbr_, kbi_, vbr_, vbi_, atr, ati);

  // 6) O-proj + gate_a + residual -> x2 (fp32)
  cgemm_kernel<1><<<dim3(64, 8), 256, 0, stream>>>(
      atr, ati, wor, woi, obr, obi, wor, woi, obr, obi, wor, woi, obr, obi,
      512, 8, 512, nullptr, nullptr, nullptr, nullptr, nullptr, nullptr,
      x_re, x_im, m_r + 1024, m_i + 1024, x2r, x2i);

  // 7) LN2 + modulate(sh_m, sc_m)
  ln_mod_kernel<<<4096, 256, 0, stream>>>(x2r, x2i, m_r, m_i, 1536, 2048, h2r, h2i);

  // 8) f1 + gelu
  cgemm_kernel<2><<<dim3(64, 32), 256, 0, stream>>>(
      h2r, h2i, wf1r, wf1i, f1br, f1bi, wf1r, wf1i, f1br, f1bi, wf1r, wf1i, f1br, f1bi,
      512, 32, 2048, f1or, f1oi, nullptr, nullptr, nullptr, nullptr,
      nullptr, nullptr, nullptr, nullptr, nullptr, nullptr);

  // 9) f2 + gate_m + residual -> d_out (2 planes)
  float* outp = (float*)d_out;
  cgemm_kernel<3><<<dim3(64, 8), 256, 0, stream>>>(
      f1or, f1oi, wf2r, wf2i, f2br, f2bi, wf2r, wf2i, f2br, f2bi, wf2r, wf2i, f2br, f2bi,
      2048, 8, 512, nullptr, nullptr, nullptr, nullptr, nullptr, nullptr,
      x2r, x2i, m_r + 2560, m_i + 2560, outp, outp + ACT);
}

// Round 5
// 415.470 us; speedup vs baseline: 1.1504x; 1.0299x over previous
//
#include <hip/hip_runtime.h>

// ---------------------------------------------------------------------------
// CDiTBlock: complex DiT block on MI355X.
// Stages: convert weights->bf16 | ada (silu+clinear, fp32) | LN1+mod ->bf16
//         QKV cgemm (q pre-scaled 0.125*log2e, V written TRANSPOSED [bh][d][t])
//         flash complex attention (global_load_lds double-buffered K/V tiles,
//             ONE barrier/tile, XOR-swizzled LDS, private-P, DPP reduce,
//             exp2-domain softmax, XCD-chunked block swizzle, 2 blocks/CU)
//         O-proj cgemm (+gate_a,+x residual, fp32) | LN2+mod ->bf16
//         f1 cgemm (+tanh-gelu) | f2 cgemm (+gate_m,+x2 residual -> d_out)
// All matmuls: bf16 MFMA 16x16x32, fp32 accum. GEMM tiles 128x64, BK=64.
// Staging everywhere: global_load_lds width=16, source-side XOR swizzle
// (chunk j fetched = j ^ (row&7)) + matching swizzle on ds_read offsets
// -> linear LDS [rows][64], fragment reads 2-way-conflict (free).
// ---------------------------------------------------------------------------

typedef unsigned short u16;
typedef __attribute__((ext_vector_type(8))) __bf16 bf16x8;
typedef __attribute__((ext_vector_type(8))) u16    u16x8;
typedef __attribute__((ext_vector_type(4))) u16    u16x4;
typedef __attribute__((ext_vector_type(4))) float  f32x4;

#define MFMA16(a, b, c) __builtin_amdgcn_mfma_f32_16x16x32_bf16(a, b, c, 0, 0, 0)

static constexpr int Bd = 4, Td = 1024, Dd = 512, Hd = 8, DHd = 64, MLPd = 2048;

__device__ __forceinline__ u16 f2bf(float x) {
  return __builtin_bit_cast(u16, (__bf16)x);
}
__device__ __forceinline__ float exp2fast(float x) {
  return __builtin_amdgcn_exp2f(x);   // v_exp_f32: D = 2^S0
}
__device__ __forceinline__ bf16x8 ldsfrag(const u16* p) {
  return __builtin_bit_cast(bf16x8, *(const u16x8*)p);
}
__device__ __forceinline__ bf16x8 gfrag(const u16* p) {
  return __builtin_bit_cast(bf16x8, *(const u16x8*)p);
}
__device__ __forceinline__ bf16x8 negbf(bf16x8 v) {
  u16x8 u = __builtin_bit_cast(u16x8, v);
  u ^= (u16)0x8000;
  return __builtin_bit_cast(bf16x8, u);
}
__device__ __forceinline__ float gelu_tanh(float x) {
  float t = tanhf(0.7978845608028654f * (x + 0.044715f * x * x * x));
  return 0.5f * x * (1.f + t);
}
// async global->LDS, 16B per lane; LDS dest = wave-uniform base + lane*16
__device__ __forceinline__ void gll16(const u16* g, u16* l) {
  __builtin_amdgcn_global_load_lds(
      (const __attribute__((address_space(1))) unsigned int*)g,
      (__attribute__((address_space(3))) unsigned int*)l, 16, 0, 0);
}

// 16-lane (DPP row) reductions via row_ror — pure VALU, no ds_swizzle.
template <int CTRL>
__device__ __forceinline__ float dppror(float x) {
  const int xi = __builtin_bit_cast(int, x);
  return __builtin_bit_cast(float,
      __builtin_amdgcn_update_dpp(xi, xi, CTRL, 0xf, 0xf, false));
}
__device__ __forceinline__ float red16max(float x) {
  x = fmaxf(x, dppror<0x128>(x));  // ror:8
  x = fmaxf(x, dppror<0x124>(x));  // ror:4
  x = fmaxf(x, dppror<0x122>(x));  // ror:2
  x = fmaxf(x, dppror<0x121>(x));  // ror:1
  return x;
}
__device__ __forceinline__ float red16sum(float x) {
  x += dppror<0x128>(x);
  x += dppror<0x124>(x);
  x += dppror<0x122>(x);
  x += dppror<0x121>(x);
  return x;
}

// ---------------- weight fp32 -> bf16 ----------------
struct CJobs {
  const float* src[12];
  u16* dst[12];
  int blk_start[13];
};
__global__ __launch_bounds__(256) void convert_kernel(CJobs J) {
  const int blk = blockIdx.x;
  int jj = 0;
  while (jj < 11 && blk >= J.blk_start[jj + 1]) ++jj;
  const int idx = (blk - J.blk_start[jj]) * 256 + threadIdx.x;
  const float4 v = ((const float4*)J.src[jj])[idx];
  u16x4 o;
  o[0] = f2bf(v.x); o[1] = f2bf(v.y); o[2] = f2bf(v.z); o[3] = f2bf(v.w);
  *(u16x4*)(J.dst[jj] + (size_t)idx * 4) = o;
}

// ---------------- ada: m = clinear(silu(c)) ----------------
__global__ __launch_bounds__(256) void ada_kernel(
    const float* __restrict__ c_re, const float* __restrict__ c_im,
    const float* __restrict__ Wr, const float* __restrict__ Wi,
    const float* __restrict__ br, const float* __restrict__ bi,
    float* __restrict__ m_r, float* __restrict__ m_i) {
  __shared__ __align__(16) float sr[512], si[512];
  const int b = blockIdx.x / 12, nb = blockIdx.x % 12;
  const int tid = threadIdx.x;
  for (int i = tid; i < 512; i += 256) {
    const float xr = c_re[b * 512 + i], xi = c_im[b * 512 + i];
    sr[i] = xr / (1.f + __expf(-xr));
    si[i] = xi / (1.f + __expf(-xi));
  }
  __syncthreads();
  const int n = nb * 256 + tid;
  const float4* wr4 = (const float4*)(Wr + (size_t)n * 512);
  const float4* wi4 = (const float4*)(Wi + (size_t)n * 512);
  const float4* sr4 = (const float4*)sr;
  const float4* si4 = (const float4*)si;
  float ar = 0.f, ai = 0.f;
  for (int k = 0; k < 128; ++k) {
    const float4 a_ = sr4[k], b_ = si4[k], u = wr4[k], v = wi4[k];
    ar += a_.x * u.x - b_.x * v.x + a_.y * u.y - b_.y * v.y +
          a_.z * u.z - b_.z * v.z + a_.w * u.w - b_.w * v.w;
    ai += b_.x * u.x + a_.x * v.x + b_.y * u.y + a_.y * v.y +
          b_.z * u.z + a_.z * v.z + b_.w * u.w + a_.w * v.w;
  }
  m_r[(size_t)b * 3072 + n] = ar + br[n] - bi[n];
  m_i[(size_t)b * 3072 + n] = ai + br[n] + bi[n];
}

// ---------------- LN + modulate -> bf16 ----------------
__global__ __launch_bounds__(256) void ln_mod_kernel(
    const float* __restrict__ xr, const float* __restrict__ xi,
    const float* __restrict__ mv_r, const float* __restrict__ mv_i,
    int off_sh, int off_sc,
    u16* __restrict__ hr, u16* __restrict__ hi) {
  const int row = blockIdx.x;          // b*1024 + t
  const int b = row >> 10;
  const int tid = threadIdx.x;
  const float* xrp = xr + (size_t)row * 512;
  const float* xip = xi + (size_t)row * 512;
  const float r0 = xrp[tid], r1 = xrp[tid + 256];
  const float i0 = xip[tid], i1 = xip[tid + 256];
  float s0 = r0 + r1, s1 = r0 * r0 + r1 * r1;
  float s2 = i0 + i1, s3 = i0 * i0 + i1 * i1;
  #pragma unroll
  for (int o = 32; o > 0; o >>= 1) {
    s0 += __shfl_down(s0, o); s1 += __shfl_down(s1, o);
    s2 += __shfl_down(s2, o); s3 += __shfl_down(s3, o);
  }
  __shared__ float red[4][4];
  if ((tid & 63) == 0) {
    const int wv = tid >> 6;
    red[wv][0] = s0; red[wv][1] = s1; red[wv][2] = s2; red[wv][3] = s3;
  }
  __syncthreads();
  s0 = red[0][0] + red[1][0] + red[2][0] + red[3][0];
  s1 = red[0][1] + red[1][1] + red[2][1] + red[3][1];
  s2 = red[0][2] + red[1][2] + red[2][2] + red[3][2];
  s3 = red[0][3] + red[1][3] + red[2][3] + red[3][3];
  const float mr = s0 * (1.f / 512.f), mi = s2 * (1.f / 512.f);
  const float vr = s1 * (1.f / 512.f) - mr * mr;
  const float vi = s3 * (1.f / 512.f) - mi * mi;
  const float rr = rsqrtf(vr + 1e-6f), ri = rsqrtf(vi + 1e-6f);
  const float* shr = mv_r + (size_t)b * 3072 + off_sh;
  const float* shi = mv_i + (size_t)b * 3072 + off_sh;
  const float* scr = mv_r + (size_t)b * 3072 + off_sc;
  const float* sci = mv_i + (size_t)b * 3072 + off_sc;
  #pragma unroll
  for (int jj = 0; jj < 2; ++jj) {
    const int n = tid + jj * 256;
    const float nr = ((jj ? r1 : r0) - mr) * rr;
    const float ni = ((jj ? i1 : i0) - mi) * ri;
    const float a = 1.f + scr[n], bb = sci[n];
    hr[(size_t)row * 512 + n] = f2bf(nr * a - ni * bb + shr[n]);
    hi[(size_t)row * 512 + n] = f2bf(nr * bb + ni * a + shi[n]);
  }
}

// ---------------- complex GEMM: out = A @ W^T (+bias, +epilogue) -----------
// A: M x K bf16 row-major (lda=K). W: N x K bf16 row-major. M=4096 fixed grid.
// Tile 128x64 (BM=128, BN=64, BK=64), 4 waves; wave w owns rows w*32..+31
// (full 64 cols): acc[2][4]. 64 MFMA-quads per K-step between barriers.
// Staging via global_load_lds with source-side XOR swizzle; LDS linear.
// EPI: 0=QKV (3 segs, bf16 out, seg0 scaled 0.125*log2e, seg2 (V) stored
//      transposed [b*512+n][1024]), 1=O-proj (gate+resid fp32), 2=f1 (gelu,
//      bf16), 3=f2 (gate+resid -> d_out planes)
template <int EPI>
__global__ __launch_bounds__(256) void cgemm_kernel(
    const u16* __restrict__ Ar, const u16* __restrict__ Ai,
    const u16* __restrict__ W0r, const u16* __restrict__ W0i,
    const float* __restrict__ b0r, const float* __restrict__ b0i,
    const u16* __restrict__ W1r, const u16* __restrict__ W1i,
    const float* __restrict__ b1r, const float* __restrict__ b1i,
    const u16* __restrict__ W2r, const u16* __restrict__ W2i,
    const float* __restrict__ b2r, const float* __restrict__ b2i,
    int K, int ntiles_per_seg, int out_ld,
    u16* __restrict__ o0r, u16* __restrict__ o0i,
    u16* __restrict__ o1r, u16* __restrict__ o1i,
    u16* __restrict__ o2r, u16* __restrict__ o2i,
    const float* __restrict__ resid_r, const float* __restrict__ resid_i,
    const float* __restrict__ gate_r, const float* __restrict__ gate_i,
    float* __restrict__ ofr, float* __restrict__ ofi) {
  const int seg = blockIdx.y / ntiles_per_seg;
  const int n0 = (blockIdx.y % ntiles_per_seg) * 64;
  const int m0 = blockIdx.x * 128;
  const u16* Wr = (seg == 0) ? W0r : (seg == 1) ? W1r : W2r;
  const u16* Wi = (seg == 0) ? W0i : (seg == 1) ? W1i : W2i;
  const float* br = (seg == 0) ? b0r : (seg == 1) ? b1r : b2r;
  const float* bi = (seg == 0) ? b0i : (seg == 1) ? b1i : b2i;
  u16* obr = (seg == 0) ? o0r : (seg == 1) ? o1r : o2r;
  u16* obi = (seg == 0) ? o0i : (seg == 1) ? o1i : o2i;

  __shared__ __align__(16) u16 sA[2][128 * 64];   // [plane][row*64+col]
  __shared__ __align__(16) u16 sB[2][64 * 64];

  const int tid = threadIdx.x;
  const int w = tid >> 6, lane = tid & 63;
  const int q4 = lane >> 4, c = lane & 15;
  const int c7 = c & 7;
  // staging coords: lane covers row r8 (0..7) of an 8-row chunk; fetches
  // swizzled 16B chunk jsw so that storage[(r,j)] = global[(r, j^(r&7))].
  const int r8 = lane >> 3, jsw = (lane & 7) ^ r8;

  const f32x4 z = {0.f, 0.f, 0.f, 0.f};
  f32x4 accR[2][4], accI[2][4];
  for (int a = 0; a < 2; ++a)
    for (int b2 = 0; b2 < 4; ++b2) { accR[a][b2] = z; accI[a][b2] = z; }

  for (int kt = 0; kt < K; kt += 64) {
    // A: wave w stages its own 32 rows, both planes (8 gll)
    #pragma unroll
    for (int j = 0; j < 4; ++j) {
      const int rr = w * 32 + j * 8;
      const size_t ga = (size_t)(m0 + rr + r8) * K + kt + jsw * 8;
      gll16(Ar + ga, &sA[0][rr * 64]);
      gll16(Ai + ga, &sA[1][rr * 64]);
    }
    // B: 16 8-row groups (64 rows x 2 planes) split across waves (4 gll)
    #pragma unroll
    for (int j = 0; j < 4; ++j) {
      const int g = w * 4 + j;
      const int pl = g >> 3, rr = (g & 7) * 8;
      const size_t gb = (size_t)(n0 + rr + r8) * K + kt + jsw * 8;
      gll16((pl ? Wi : Wr) + gb, &sB[pl][rr * 64]);
    }
    __syncthreads();   // drains vmcnt (gll) + joins waves
    #pragma unroll
    for (int kc = 0; kc < 2; ++kc) {
      bf16x8 a_r[2], a_i[2], a_n[2];
      #pragma unroll
      for (int mi = 0; mi < 2; ++mi) {
        const int off = (w * 32 + mi * 16 + c) * 64 + (((kc * 4 + q4) ^ c7) * 8);
        a_r[mi] = ldsfrag(&sA[0][off]);
        a_i[mi] = ldsfrag(&sA[1][off]);
        a_n[mi] = negbf(a_i[mi]);
      }
      #pragma unroll
      for (int ni = 0; ni < 4; ++ni) {
        const int off = (ni * 16 + c) * 64 + (((kc * 4 + q4) ^ c7) * 8);
        const bf16x8 b_r = ldsfrag(&sB[0][off]);
        const bf16x8 b_i = ldsfrag(&sB[1][off]);
        #pragma unroll
        for (int mi = 0; mi < 2; ++mi) {
          accR[mi][ni] = MFMA16(a_r[mi], b_r, accR[mi][ni]);
          accR[mi][ni] = MFMA16(a_n[mi], b_i, accR[mi][ni]);
          accI[mi][ni] = MFMA16(a_i[mi], b_r, accI[mi][ni]);
          accI[mi][ni] = MFMA16(a_r[mi], b_i, accI[mi][ni]);
        }
      }
    }
    __syncthreads();
  }

  // q scale folds 1/sqrt(DH) AND log2(e) (softmax runs in exp2 domain)
  const float scale = (EPI == 0 && seg == 0) ? 0.18033688011112042f : 1.f;
  #pragma unroll
  for (int mi = 0; mi < 2; ++mi)
    #pragma unroll
    for (int ni = 0; ni < 4; ++ni) {
      const int n = n0 + ni * 16 + c;
      const float biasr = br[n] - bi[n];
      const float biasi = br[n] + bi[n];
      if (EPI == 0 && seg == 2) {
        // V: transposed store -> [b*512 + n][1024] at t.
        const int m = m0 + w * 32 + mi * 16 + q4 * 4;
        u16x4 pr, pi;
        #pragma unroll
        for (int r = 0; r < 4; ++r) {
          pr[r] = f2bf(accR[mi][ni][r] + biasr);
          pi[r] = f2bf(accI[mi][ni][r] + biasi);
        }
        const size_t o = ((size_t)((m >> 10) * 512 + n)) * 1024 + (m & 1023);
        *(u16x4*)(obr + o) = pr;
        *(u16x4*)(obi + o) = pi;
        continue;
      }
      #pragma unroll
      for (int r = 0; r < 4; ++r) {
        const int m = m0 + w * 32 + mi * 16 + q4 * 4 + r;
        const float ore = accR[mi][ni][r] + biasr;
        const float oim = accI[mi][ni][r] + biasi;
        if (EPI == 0) {
          obr[(size_t)m * out_ld + n] = f2bf(ore * scale);
          obi[(size_t)m * out_ld + n] = f2bf(oim * scale);
        } else if (EPI == 2) {
          obr[(size_t)m * out_ld + n] = f2bf(gelu_tanh(ore));
          obi[(size_t)m * out_ld + n] = f2bf(gelu_tanh(oim));
        } else {  // 1 or 3: gate + residual, fp32 out
          const int bb = m >> 10;
          const float gr = gate_r[(size_t)bb * 3072 + n];
          const float gi = gate_i[(size_t)bb * 3072 + n];
          const size_t o = (size_t)m * 512 + n;
          ofr[o] = resid_r[o] + ore * gr - oim * gi;
          ofi[o] = resid_i[o] + ore * gi + oim * gr;
        }
      }
    }
}

// ---------------- flash complex attention ----------------
// grid (T/64, B*H); block 256 (4 waves, 16 q-rows each). Q pre-scaled.
// XCD-chunked block swizzle: 64 consecutive work-ids (4 bh, KV 2MB -> L2-fit)
// per XCD. K/V^T tiles via global_load_lds, double-buffered swizzled LDS,
// ONE barrier per k-tile. P via per-wave private LDS (16x64 swizzled).
// LDS total 81920 B -> 2 blocks/CU. exp2-domain softmax, DPP reductions.
__global__ __launch_bounds__(256, 2) void attn_kernel(
    const u16* __restrict__ Qr, const u16* __restrict__ Qi,
    const u16* __restrict__ Kr, const u16* __restrict__ Ki,
    const u16* __restrict__ Vtr, const u16* __restrict__ Vti,
    u16* __restrict__ Or, u16* __restrict__ Oi) {
  __shared__ __align__(16) u16 sK[2][2][64 * 64];   // [buf][plane][row*64+col]
  __shared__ __align__(16) u16 sV[2][2][64 * 64];   // V^T: row=d, col=token
  __shared__ __align__(16) u16 sP[2][4][16 * 64];   // [plane][wave], swizzled

  const int tid = threadIdx.x;
  const int w = tid >> 6, lane = tid & 63;
  const int q4 = lane >> 4, c = lane & 15;
  const int c7 = c & 7;
  // XCD-chunked swizzle over 512 blocks (8 XCDs x 64)
  const int id = blockIdx.y * 16 + blockIdx.x;
  const int swz = (id & 7) * 64 + (id >> 3);
  const int bh = swz >> 4, b = bh >> 3, h = bh & 7;
  const int t0 = (swz & 15) * 64;
  const size_t base = (size_t)b * Td * Dd + h * DHd;
  const size_t vbase = (size_t)bh << 16;            // bh * 64 * 1024
  const int r8 = lane >> 3, jsw = (lane & 7) ^ r8;

  // Q fragments direct from global (once)
  bf16x8 aQr[2], aQi[2], aQn[2];
  #pragma unroll
  for (int kc = 0; kc < 2; ++kc) {
    const size_t g = base + (size_t)(t0 + w * 16 + c) * Dd + kc * 32 + q4 * 8;
    aQr[kc] = gfrag(Qr + g);
    aQi[kc] = gfrag(Qi + g);
    aQn[kc] = negbf(aQi[kc]);
  }

  float mst[2][4], lst[2][4];
  #pragma unroll
  for (int p = 0; p < 2; ++p)
    for (int r = 0; r < 4; ++r) { mst[p][r] = -1e30f; lst[p][r] = 0.f; }
  const f32x4 z = {0.f, 0.f, 0.f, 0.f};
  f32x4 U1[4], U2[4], U3[4], U4[4];
  for (int i = 0; i < 4; ++i) { U1[i] = z; U2[i] = z; U3[i] = z; U4[i] = z; }

  u16* const pR = &sP[0][w][0];
  u16* const pI = &sP[1][w][0];

  auto stage = [&](int kt, int bi) {
    #pragma unroll
    for (int half = 0; half < 2; ++half) {
      const int rr = w * 16 + half * 8;             // wave-uniform base row
      const size_t gk = base + (size_t)(kt * 64 + rr + r8) * Dd + jsw * 8;
      gll16(Kr + gk, &sK[bi][0][rr * 64]);
      gll16(Ki + gk, &sK[bi][1][rr * 64]);
      const size_t gv = vbase + (size_t)(rr + r8) * Td + kt * 64 + jsw * 8;
      gll16(Vtr + gv, &sV[bi][0][rr * 64]);
      gll16(Vti + gv, &sV[bi][1][rr * 64]);
    }
  };

  stage(0, 0);

  for (int kt = 0; kt < 16; ++kt) {
    __syncthreads();                 // drains gll for buf[kt&1]; joins waves
    if (kt < 15) stage(kt + 1, (kt + 1) & 1);   // async prefetch, other buffer
    const int bi = kt & 1;

    // ---- QK^T ----
    f32x4 S[2][4];
    __builtin_amdgcn_s_setprio(1);
    #pragma unroll
    for (int nb = 0; nb < 4; ++nb) {
      f32x4 tr = z, ti = z;
      #pragma unroll
      for (int kc = 0; kc < 2; ++kc) {
        const int off = (nb * 16 + c) * 64 + (((kc * 4 + q4) ^ c7) * 8);
        const bf16x8 bKr = ldsfrag(&sK[bi][0][off]);
        const bf16x8 bKi = ldsfrag(&sK[bi][1][off]);
        tr = MFMA16(aQr[kc], bKr, tr);
        tr = MFMA16(aQn[kc], bKi, tr);
        ti = MFMA16(aQi[kc], bKr, ti);
        ti = MFMA16(aQr[kc], bKi, ti);
      }
      S[0][nb] = tr; S[1][nb] = ti;
    }
    __builtin_amdgcn_s_setprio(0);

    // ---- online softmax (exp2 domain, DPP reductions) ----
    float alpha[2][4];
    #pragma unroll
    for (int p = 0; p < 2; ++p) {
      u16* const pp = (p == 0) ? pR : pI;
      float rs[4];
      #pragma unroll
      for (int r = 0; r < 4; ++r) {
        float tm = fmaxf(fmaxf(S[p][0][r], S[p][1][r]), fmaxf(S[p][2][r], S[p][3][r]));
        tm = red16max(tm);
        const float mn = fmaxf(mst[p][r], tm);
        alpha[p][r] = exp2fast(mst[p][r] - mn);
        mst[p][r] = mn;
        rs[r] = 0.f;
      }
      #pragma unroll
      for (int nb = 0; nb < 4; ++nb)
        #pragma unroll
        for (int r = 0; r < 4; ++r) {
          const float pv = exp2fast(S[p][nb][r] - mst[p][r]);
          rs[r] += pv;
          const int row = q4 * 4 + r;
          pp[row * 64 + ((nb * 16 + c) ^ ((row & 7) << 3))] = f2bf(pv);
        }
      #pragma unroll
      for (int r = 0; r < 4; ++r)
        lst[p][r] = lst[p][r] * alpha[p][r] + red16sum(rs[r]);
    }
    #pragma unroll
    for (int i = 0; i < 4; ++i)
      #pragma unroll
      for (int r = 0; r < 4; ++r) {
        U1[i][r] *= alpha[0][r]; U2[i][r] *= alpha[0][r];
        U3[i][r] *= alpha[1][r]; U4[i][r] *= alpha[1][r];
      }

    // ---- PV (P via own-wave LDS round-trip; V from swizzled LDS) ----
    asm volatile("s_waitcnt lgkmcnt(0)" ::: "memory");  // P stores drained
    __builtin_amdgcn_s_setprio(1);
    #pragma unroll
    for (int kc = 0; kc < 2; ++kc) {
      const int poff = c * 64 + (((kc * 4 + q4) ^ c7) * 8);
      const bf16x8 aPr = ldsfrag(pR + poff);
      const bf16x8 aPi = ldsfrag(pI + poff);
      #pragma unroll
      for (int nd = 0; nd < 4; ++nd) {
        const int voff = (nd * 16 + c) * 64 + (((kc * 4 + q4) ^ c7) * 8);
        const bf16x8 bVr = ldsfrag(&sV[bi][0][voff]);
        const bf16x8 bVi = ldsfrag(&sV[bi][1][voff]);
        U1[nd] = MFMA16(aPr, bVr, U1[nd]);
        U2[nd] = MFMA16(aPr, bVi, U2[nd]);
        U3[nd] = MFMA16(aPi, bVr, U3[nd]);
        U4[nd] = MFMA16(aPi, bVi, U4[nd]);
      }
    }
    __builtin_amdgcn_s_setprio(0);
  }

  #pragma unroll
  for (int nd = 0; nd < 4; ++nd)
    #pragma unroll
    for (int r = 0; r < 4; ++r) {
      const int trow = t0 + w * 16 + q4 * 4 + r;
      const int d = nd * 16 + c;
      const float ilre = 1.f / lst[0][r], ilim = 1.f / lst[1][r];
      const float ore = U1[nd][r] * ilre - U4[nd][r] * ilim;
      const float oim = U2[nd][r] * ilre + U3[nd][r] * ilim;
      const size_t g = base + (size_t)trow * Dd + d;
      Or[g] = f2bf(ore);
      Oi[g] = f2bf(oim);
    }
}

// ---------------------------------------------------------------------------
extern "C" void kernel_launch(void* const* d_in, const int* in_sizes, int n_in,
                              void* d_out, int out_size, void* d_ws, size_t ws_size,
                              hipStream_t stream) {
  const float* x_re  = (const float*)d_in[0];
  const float* x_im  = (const float*)d_in[1];
  const float* c_re  = (const float*)d_in[2];
  const float* c_im  = (const float*)d_in[3];
  const float* adaWr = (const float*)d_in[4];
  const float* adaWi = (const float*)d_in[5];
  const float* adabr = (const float*)d_in[6];
  const float* adabi = (const float*)d_in[7];
  const float* qWr = (const float*)d_in[8],  *qWi = (const float*)d_in[9];
  const float* qbr = (const float*)d_in[10], *qbi = (const float*)d_in[11];
  const float* kWr = (const float*)d_in[12], *kWi = (const float*)d_in[13];
  const float* kbr = (const float*)d_in[14], *kbi = (const float*)d_in[15];
  const float* vWr = (const float*)d_in[16], *vWi = (const float*)d_in[17];
  const float* vbr = (const float*)d_in[18], *vbi = (const float*)d_in[19];
  const float* oWr = (const float*)d_in[20], *oWi = (const float*)d_in[21];
  const float* obr = (const float*)d_in[22], *obi = (const float*)d_in[23];
  const float* f1Wr = (const float*)d_in[24], *f1Wi = (const float*)d_in[25];
  const float* f1br = (const float*)d_in[26], *f1bi = (const float*)d_in[27];
  const float* f2Wr = (const float*)d_in[28], *f2Wi = (const float*)d_in[29];
  const float* f2br = (const float*)d_in[30], *f2bi = (const float*)d_in[31];

  char* wsp = (char*)d_ws;
  size_t off = 0;
  auto alloc = [&](size_t bytes) -> void* {
    void* p = wsp + off;
    off += (bytes + 255) & ~(size_t)255;
    return p;
  };
  const size_t WQ = 512 * 512, WF = 2048 * 512;   // elements
  u16* wqr = (u16*)alloc(WQ * 2); u16* wqi = (u16*)alloc(WQ * 2);
  u16* wkr = (u16*)alloc(WQ * 2); u16* wki = (u16*)alloc(WQ * 2);
  u16* wvr = (u16*)alloc(WQ * 2); u16* wvi = (u16*)alloc(WQ * 2);
  u16* wor = (u16*)alloc(WQ * 2); u16* woi = (u16*)alloc(WQ * 2);
  u16* wf1r = (u16*)alloc(WF * 2); u16* wf1i = (u16*)alloc(WF * 2);
  u16* wf2r = (u16*)alloc(WF * 2); u16* wf2i = (u16*)alloc(WF * 2);
  float* m_r = (float*)alloc(4 * 3072 * 4);
  float* m_i = (float*)alloc(4 * 3072 * 4);
  const size_t ACT = (size_t)Bd * Td * Dd;        // 2,097,152 elements
  u16* h1r = (u16*)alloc(ACT * 2); u16* h1i = (u16*)alloc(ACT * 2);
  u16* qbr_ = (u16*)alloc(ACT * 2); u16* qbi_ = (u16*)alloc(ACT * 2);
  u16* kbr_ = (u16*)alloc(ACT * 2); u16* kbi_ = (u16*)alloc(ACT * 2);
  u16* vbr_ = (u16*)alloc(ACT * 2); u16* vbi_ = (u16*)alloc(ACT * 2);
  u16* atr = (u16*)alloc(ACT * 2); u16* ati = (u16*)alloc(ACT * 2);
  float* x2r = (float*)alloc(ACT * 4); float* x2i = (float*)alloc(ACT * 4);
  // aliases (dead buffers reused)
  u16* h2r = h1r; u16* h2i = h1i;                 // h1 dead after QKV
  u16* f1or = qbr_;                               // q..attn (32MB) dead after O-proj
  u16* f1oi = qbr_ + (size_t)Bd * Td * MLPd;

  // 1) weights -> bf16
  CJobs J;
  const float* wsrc[12] = {qWr, qWi, kWr, kWi, vWr, vWi, oWr, oWi, f1Wr, f1Wi, f2Wr, f2Wi};
  u16* wdst[12] = {wqr, wqi, wkr, wki, wvr, wvi, wor, woi, wf1r, wf1i, wf2r, wf2i};
  int cum = 0;
  for (int j = 0; j < 12; ++j) {
    J.src[j] = wsrc[j]; J.dst[j] = wdst[j]; J.blk_start[j] = cum;
    cum += (j < 8 ? (int)WQ : (int)WF) / 1024;
  }
  J.blk_start[12] = cum;  // 6144
  convert_kernel<<<cum, 256, 0, stream>>>(J);

  // 2) ada modulation vectors
  ada_kernel<<<48, 256, 0, stream>>>(c_re, c_im, adaWr, adaWi, adabr, adabi, m_r, m_i);

  // 3) LN1 + modulate(sh_a, sc_a)
  ln_mod_kernel<<<4096, 256, 0, stream>>>(x_re, x_im, m_r, m_i, 0, 512, h1r, h1i);

  // 4) QKV (q scaled by 0.125*log2e; V stored transposed [bh][d][t])
  cgemm_kernel<0><<<dim3(32, 24), 256, 0, stream>>>(
      h1r, h1i, wqr, wqi, qbr, qbi, wkr, wki, kbr, kbi, wvr, wvi, vbr, vbi,
      512, 8, 512, qbr_, qbi_, kbr_, kbi_, vbr_, vbi_,
      nullptr, nullptr, nullptr, nullptr, nullptr, nullptr);

  // 5) attention (V^T layout input)
  attn_kernel<<<dim3(16, 32), 256, 0, stream>>>(qbr_, qbi_, kbr_, kbi_, vbr_, vbi_, atr, ati);

  // 6) O-proj + gate_a + residual -> x2 (fp32)
  cgemm_kernel<1><<<dim3(32, 8), 256, 0, stream>>>(
      atr, ati, wor, woi, obr, obi, wor, woi, obr, obi, wor, woi, obr, obi,
      512, 8, 512, nullptr, nullptr, nullptr, nullptr, nullptr, nullptr,
      x_re, x_im, m_r + 1024, m_i + 1024, x2r, x2i);

  // 7) LN2 + modulate(sh_m, sc_m)
  ln_mod_kernel<<<4096, 256, 0, stream>>>(x2r, x2i, m_r, m_i, 1536, 2048, h2r, h2i);

  // 8) f1 + gelu
  cgemm_kernel<2><<<dim3(32, 32), 256, 0, stream>>>(
      h2r, h2i, wf1r, wf1i, f1br, f1bi, wf1r, wf1i, f1br, f1bi, wf1r, wf1i, f1br, f1bi,
      512, 32, 2048, f1or, f1oi, nullptr, nullptr, nullptr, nullptr,
      nullptr, nullptr, nullptr, nullptr, nullptr, nullptr);

  // 9) f2 + gate_m + residual -> d_out (2 planes)
  float* outp = (float*)d_out;
  cgemm_kernel<3><<<dim3(32, 8), 256, 0, stream>>>(
      f1or, f1oi, wf2r, wf2i, f2br, f2bi, wf2r, wf2i, f2br, f2bi, wf2r, wf2i, f2br, f2bi,
      2048, 8, 512, nullptr, nullptr, nullptr, nullptr, nullptr, nullptr,
      x2r, x2i, m_r + 2560, m_i + 2560, outp, outp + ACT);
}